// Round 1
// baseline (328.568 us; speedup 1.0000x reference)
//
#include <hip/hip_runtime.h>

// TriDiagonalLaplaceSolver: B=4096 independent rows, N=8192 per row.
// Thomas algorithm with precomputed LU factors a (N), b (N-1), c (N-1).
//   fwd: y[i] = x[i] - c[i-1]*y[i-1]        (y[0] = x[0])
//   bwd: z[i] = (y[i] - b[i]*z[i+1])/a[i]   (z[N-1] = y[N-1]/a[N-1])
// Contraction ratio ~0.268/step => HALO=16 zero-init warm-up reproduces
// exact state to ~7e-10 relative.
//
// R3 (this version): the R2 kernel was address-pattern-bound, not BW-bound
// (VALUBusy 5.5%, HBM 39% of peak): lanes were 32KB apart on every global
// access (64 lines per wave instr), and WRITE_SIZE showed +100MB of scratch
// (VGPR_Count=64 < the 80-float window).  Fix:
//  - Block = 32 rows x 4 chunks.  x tile (32 x 288, shared halos: read amp
//    1.5x -> 1.125x) staged via LDS with linear-index float4 loads ->
//    fully coalesced global reads.
//  - XOR swizzle (c4 ^ (row&7)) on the LDS f4 index: both the coalesced
//    staging writes and the per-thread stride-288 reads hit all 32 banks.
//  - z overwrites the consumed x tile after a barrier; store-out is one
//    contiguous 1KB segment per wave instr -> fully coalesced writes.
//  - c/b/rcp(a) staged zero-padded in LDS: FIRST/EDGE branches vanish
//    (warm-ups through the zero pad are exact no-ops), zero divergence.
//  - __launch_bounds__(128,2): 256-VGPR cap so ybuf stays in registers.
// LDS 40.3 KB/block -> 4 blocks/CU = 8 waves/CU.

#define NN    8192
#define BB    4096
#define ROWS  32                         // rows per block
#define CCOL  4                          // chunks per block
#define CHUNK 64
#define HALO  16
#define TILE_F   (CCOL*CHUNK + 2*HALO)   // 288 floats per tile row
#define TILE_F4  (TILE_F/4)              // 72
#define WIN      (CHUNK + HALO)          // 80 floats live in VGPRs per thread
#define NTHR     (ROWS*CCOL)             // 128 threads

typedef float yvec_t __attribute__((ext_vector_type(WIN)));

__device__ __forceinline__ float fast_rcp(float v) {
    float r = __builtin_amdgcn_rcpf(v);
    return r * (2.0f - v * r);           // one NR step -> ~0.5 ulp
}

__global__ __launch_bounds__(NTHR, 2) void TriDiagonalLaplaceSolver_kernel(
    const float* __restrict__ x,
    const float* __restrict__ a,
    const float* __restrict__ b,
    const float* __restrict__ c,
    float* __restrict__ out)
{
    __shared__ float4 tile[ROWS * TILE_F4];       // 36 KB, x then z (reused)
    __shared__ __align__(16) float scm[TILE_F];   // c[G-1], 0 outside [1,N-1]
    __shared__ __align__(16) float srb[TILE_F];   // b[G],   0 outside [0,N-2]
    __shared__ __align__(16) float sra[TILE_F];   // 1/a[G], 0 outside [0,N-1]

    const int t  = threadIdx.x;
    const int g  = blockIdx.x;                    // chunk group, 0..31
    const int r0 = blockIdx.y * ROWS;             // first row of tile
    const int S0 = g * (CCOL*CHUNK) - HALO;       // global col of tile col 0

    // ---- stage coefficient slices (zero-padded => no FIRST/EDGE cases) ----
    for (int j = t; j < TILE_F; j += NTHR) {
        const int G = S0 + j;
        scm[j] = (G >= 1 && G <= NN-1) ? c[G-1]         : 0.0f;
        srb[j] = (G >= 0 && G <= NN-2) ? b[G]           : 0.0f;
        sra[j] = (G >= 0 && G <= NN-1) ? fast_rcp(a[G]) : 0.0f;
    }

    // ---- stage x tile: coalesced float4 loads, XOR-swizzled LDS layout ----
    const float4* __restrict__ x4 = (const float4*)x;
    const int S4 = (S0 >> 2);                     // S0 is a multiple of 16
    #pragma unroll
    for (int it = 0; it < (ROWS*TILE_F4)/NTHR; ++it) {   // 18 iters
        const int i  = it*NTHR + t;
        const int rr = i / TILE_F4;               // 0..31
        const int c4 = i - rr*TILE_F4;            // 0..71
        const int G4 = S4 + c4;
        float4 v = make_float4(0.0f, 0.0f, 0.0f, 0.0f);
        if (G4 >= 0 && G4 < NN/4)
            v = x4[(r0 + rr) * (NN/4) + G4];
        tile[rr*TILE_F4 + (c4 ^ (rr & 7))] = v;   // bijective in 8-f4 groups
    }
    __syncthreads();

    // ---- per-thread Thomas solve on one 64-col chunk of one row ----
    const int row = t & (ROWS-1);
    const int cc  = t >> 5;                       // chunk column 0..3
    const int sw  = row & 7;
    const int tb  = row * TILE_F4;
    const int cb  = cc * CHUNK;                   // tile col of warm-up start
    const int cb4 = cb >> 2;

    // forward: warm-up over [cb, cb+16) (q<4, values discarded; zero pad
    // makes the g==0/cc==0 warm-up an exact no-op), main over [cb+16, cb+96)
    float y = 0.0f;
    yvec_t ybuf;
    #pragma unroll
    for (int q = 0; q < (HALO + WIN)/4; ++q) {    // 24 f4
        const float4 xv = tile[tb + ((cb4 + q) ^ sw)];
        const float4 cm = *(const float4*)&scm[cb + 4*q];
        const float y0 = xv.x - cm.x * y;
        const float y1 = xv.y - cm.y * y0;
        const float y2 = xv.z - cm.z * y1;
        const float y3 = xv.w - cm.w * y2;
        y = y3;
        if (q >= HALO/4) {                        // compile-time predicate
            const int k = 4*q - HALO;
            ybuf[k] = y0; ybuf[k+1] = y1; ybuf[k+2] = y2; ybuf[k+3] = y3;
        }
    }

    // backward: warm-up over k in [64,80) (discarded; zero-padded srb/sra
    // make the last-chunk warm-up exact), main k in [0,64) into ybuf
    float z = 0.0f;
    #pragma unroll
    for (int q = WIN/4 - 1; q >= 0; --q) {        // 19..0
        const int colf = cb + HALO + 4*q;
        const float4 bv = *(const float4*)&srb[colf];
        const float4 rv = *(const float4*)&sra[colf];
        const int k = 4*q;
        const float z3 = (ybuf[k+3] - bv.w * z ) * rv.w;
        const float z2 = (ybuf[k+2] - bv.z * z3) * rv.z;
        const float z1 = (ybuf[k+1] - bv.y * z2) * rv.y;
        const float z0 = (ybuf[k+0] - bv.x * z1) * rv.x;
        z = z0;
        if (q < CHUNK/4) {                        // compile-time predicate
            ybuf[k] = z0; ybuf[k+1] = z1; ybuf[k+2] = z2; ybuf[k+3] = z3;
        }
    }

    __syncthreads();   // all tile x reads done before z overwrites it

    // ---- z back to LDS (swizzled), then coalesced store-out ----
    #pragma unroll
    for (int q = 0; q < CHUNK/4; ++q) {
        float4 zv;
        zv.x = ybuf[4*q];   zv.y = ybuf[4*q+1];
        zv.z = ybuf[4*q+2]; zv.w = ybuf[4*q+3];
        tile[tb + ((cb4 + HALO/4 + q) ^ sw)] = zv;
    }
    __syncthreads();

    float4* __restrict__ o4 = (float4*)out;
    #pragma unroll
    for (int it = 0; it < (ROWS*CCOL*CHUNK/4)/NTHR; ++it) {  // 16 iters
        const int i   = it*NTHR + t;
        const int rr  = i >> 6;                   // 64 f4 per out row
        const int c4o = i & 63;
        const float4 v = tile[rr*TILE_F4 + ((c4o + HALO/4) ^ (rr & 7))];
        o4[(r0 + rr) * (NN/4) + g*(CCOL*CHUNK/4) + c4o] = v;  // 1KB/wave instr
    }
}

extern "C" void kernel_launch(void* const* d_in, const int* in_sizes, int n_in,
                              void* d_out, int out_size, void* d_ws, size_t ws_size,
                              hipStream_t stream) {
    const float* x = (const float*)d_in[0];
    const float* a = (const float*)d_in[1];
    const float* b = (const float*)d_in[2];
    const float* c = (const float*)d_in[3];
    float* out = (float*)d_out;

    dim3 grid(NN / (CCOL*CHUNK), BB / ROWS);   // 32 x 128 = 4096 blocks
    dim3 block(NTHR);                          // 128 threads = 2 waves
    TriDiagonalLaplaceSolver_kernel<<<grid, block, 0, stream>>>(x, a, b, c, out);
}

// Round 4
// 275.667 us; speedup vs baseline: 1.1919x; 1.1919x over previous
//
#include <hip/hip_runtime.h>

// TriDiagonalLaplaceSolver: B=4096 rows, N=8192 per row.
// Thomas algorithm with precomputed LU factors a (N), b (N-1), c (N-1).
//   fwd: y[i] = x[i] - c[i-1]*y[i-1]        (y[0] = x[0])
//   bwd: z[i] = (y[i] - b[i]*z[i+1])/a[i]   (z[N-1] = y[N-1]/a[N-1])
// Contraction ~0.268/step => HALO=16 zero-init warm-up reproduces exact
// state to ~1e-9 relative.
//
// R6: R5 failed correctness (absmax 2.56) from ONE index bug:
//   wb4 = cc*(CHUNK/4)*2  (= 16*cc)  but the warm-up start tile column is
//   cc*CHUNK floats = 8*cc float4s.  The stray *2 came from R3's CHUNK=64
//   geometry.  Chunks cc>=1 solved the wrong columns, and cc>=9 read past
//   the LDS block (also the likely cause of R4's container crash).
// Fix: wb4 = cc*(CHUNK/4).  All other R5 structure kept (unrefuted):
//  - Prep kernel writes zero-PADDED, position-aligned coefficient arrays
//    into __device__ globals: g_cm[p+16]=c[p-1], g_bp[p+16]=b[p],
//    g_ra[p+16]=1/a[p], zeros outside valid range. ~97KB, L2-resident,
//    idempotent under graph replay. Hot loops have NO selects/clamps/rcp.
//  - Block = 256 thr = 16 rows x 16 chunks of 32; x tile 16x544 floats =
//    34816 B LDS -> 4 blocks/CU = 16 waves/CU (50% occupancy cap).
//  - Coalesced float4 staging with XOR-swizzled LDS; z overwrites the
//    consumed x tile; coalesced 1KB/wave-instr store-out.

#define NN    8192
#define BB    4096
#define ROWS  16                         // rows per block
#define CCOL  16                         // chunks per block
#define CHUNK 32
#define HALO  16
#define TILE_F   (CCOL*CHUNK + 2*HALO)   // 544 floats per tile row
#define TILE_F4  (TILE_F/4)              // 136
#define WIN      (CHUNK + HALO)          // 48 floats live in VGPRs per thread
#define NTHR     (ROWS*CCOL)             // 256 threads
#define PADN     (NN + 2*HALO + 32)      // 8256 floats per padded coef array

typedef float yvec_t __attribute__((ext_vector_type(WIN)));

// Padded coefficient arrays, indexed by (position + HALO).
__device__ __align__(16) float g_cm[PADN];   // c[p-1], 0 outside [1, NN-1]
__device__ __align__(16) float g_bp[PADN];   // b[p],   0 outside [0, NN-2]
__device__ __align__(16) float g_ra[PADN];   // 1/a[p], 0 outside [0, NN-1]

__global__ void TriDiag_prep_kernel(
    const float* __restrict__ a,
    const float* __restrict__ b,
    const float* __restrict__ c)
{
    const int i = blockIdx.x * 256 + threadIdx.x;
    if (i >= PADN) return;
    const int p = i - HALO;              // position this slot represents
    g_cm[i] = (p >= 1 && p <= NN-1) ? c[p-1]    : 0.0f;
    g_bp[i] = (p >= 0 && p <= NN-2) ? b[p]      : 0.0f;
    g_ra[i] = (p >= 0 && p <= NN-1) ? 1.0f/a[p] : 0.0f;
}

__global__ __launch_bounds__(NTHR, 4) void TriDiagonalLaplaceSolver_kernel(
    const float* __restrict__ x,
    float* __restrict__ out)
{
    __shared__ float4 tile[ROWS * TILE_F4];       // 34816 B; x then z (reused)

    const int t  = threadIdx.x;
    const int g  = blockIdx.x;                    // chunk group, 0..15
    const int r0 = blockIdx.y * ROWS;             // first row of tile
    const int S0 = g * (CCOL*CHUNK) - HALO;       // global col of tile col 0
    const int S4 = S0 >> 2;

    // ---- stage x tile: coalesced float4 loads, XOR-swizzled LDS layout ----
    const float4* __restrict__ x4 = (const float4*)x;
    for (int i = t; i < ROWS*TILE_F4; i += NTHR) {       // 8.5 iters
        const int rr = i / TILE_F4;
        const int c4 = i - rr*TILE_F4;
        const int G4 = S4 + c4;
        float4 v = make_float4(0.0f, 0.0f, 0.0f, 0.0f);
        if ((unsigned)G4 < (unsigned)(NN/4))
            v = x4[(size_t)(r0 + rr) * (NN/4) + G4];
        tile[rr*TILE_F4 + (c4 ^ (rr & 7))] = v;   // bijective in 8-f4 groups
    }
    __syncthreads();

    // ---- per-thread Thomas solve on one 32-col chunk of one row ----
    const int row = t & (ROWS-1);
    const int cc  = t >> 4;                       // chunk column 0..15
    const int sw  = row & 7;
    const int tb  = row * TILE_F4;
    const int wb4 = cc * (CHUNK/4);               // 8*cc: warm-up start f4 col
    const int cb4 = wb4 + HALO/4;                 // chunk start f4 col
    // padded-array index of the warm-up start position (Sg = g*512+cc*32-16):
    const int Jf0 = g*(CCOL*CHUNK) + cc*CHUNK;    // = Sg + HALO, mult of 4

    // forward: warm-up q<4 (values discarded; zero-padded multipliers make
    // the g==0,cc==0 warm-up an exact no-op), main q>=4 into ybuf.
    float y = 0.0f;
    yvec_t ybuf;
    #pragma unroll
    for (int q = 0; q < (HALO + WIN)/4; ++q) {    // 16 f4
        const float4 xv  = tile[tb + ((wb4 + q) ^ sw)];
        const float4 cmv = *(const float4*)&g_cm[Jf0 + 4*q];
        const float y0 = xv.x - cmv.x * y;
        const float y1 = xv.y - cmv.y * y0;
        const float y2 = xv.z - cmv.z * y1;
        const float y3 = xv.w - cmv.w * y2;
        y = y3;
        if (q >= HALO/4) {                        // compile-time predicate
            const int k = 4*q - HALO;
            ybuf[k] = y0; ybuf[k+1] = y1; ybuf[k+2] = y2; ybuf[k+3] = y3;
        }
    }

    // backward: warm-up k in [32,48) (discarded; zero-padded b/ra make the
    // last-chunk warm-up exact and give z[N-1]=y[N-1]/a[N-1]), main k<32.
    float z = 0.0f;
    #pragma unroll
    for (int q = WIN/4 - 1; q >= 0; --q) {        // 11..0
        const int j = Jf0 + HALO + 4*q;           // padded idx of ybuf[4q]'s pos
        const float4 bv = *(const float4*)&g_bp[j];
        const float4 rv = *(const float4*)&g_ra[j];
        const int k = 4*q;
        const float z3 = (ybuf[k+3] - bv.w * z ) * rv.w;
        const float z2 = (ybuf[k+2] - bv.z * z3) * rv.z;
        const float z1 = (ybuf[k+1] - bv.y * z2) * rv.y;
        const float z0 = (ybuf[k+0] - bv.x * z1) * rv.x;
        z = z0;
        if (q < CHUNK/4) {                        // compile-time predicate
            ybuf[k] = z0; ybuf[k+1] = z1; ybuf[k+2] = z2; ybuf[k+3] = z3;
        }
    }

    __syncthreads();   // all tile x reads done before z overwrites it

    // ---- z back to LDS (swizzled), then coalesced store-out ----
    #pragma unroll
    for (int q = 0; q < CHUNK/4; ++q) {
        float4 zv;
        zv.x = ybuf[4*q];   zv.y = ybuf[4*q+1];
        zv.z = ybuf[4*q+2]; zv.w = ybuf[4*q+3];
        tile[tb + ((cb4 + q) ^ sw)] = zv;
    }
    __syncthreads();

    float4* __restrict__ o4 = (float4*)out;
    #pragma unroll
    for (int it = 0; it < (ROWS*CCOL*CHUNK/4)/NTHR; ++it) {  // 8 iters
        const int i   = it*NTHR + t;
        const int rr  = i >> 7;                   // 128 f4 per out row
        const int c4o = i & 127;
        const float4 v = tile[rr*TILE_F4 + ((c4o + HALO/4) ^ (rr & 7))];
        o4[(size_t)(r0 + rr) * (NN/4) + g*(CCOL*CHUNK/4) + c4o] = v;
    }
}

extern "C" void kernel_launch(void* const* d_in, const int* in_sizes, int n_in,
                              void* d_out, int out_size, void* d_ws, size_t ws_size,
                              hipStream_t stream) {
    const float* x = (const float*)d_in[0];
    const float* a = (const float*)d_in[1];
    const float* b = (const float*)d_in[2];
    const float* c = (const float*)d_in[3];
    float* out = (float*)d_out;

    TriDiag_prep_kernel<<<dim3((PADN + 255)/256), dim3(256), 0, stream>>>(a, b, c);

    dim3 grid(NN / (CCOL*CHUNK), BB / ROWS);   // 16 x 256 = 4096 blocks
    dim3 block(NTHR);                          // 256 threads = 4 waves
    TriDiagonalLaplaceSolver_kernel<<<grid, block, 0, stream>>>(x, out);
}

// Round 5
// 254.550 us; speedup vs baseline: 1.2908x; 1.0830x over previous
//
#include <hip/hip_runtime.h>

// TriDiagonalLaplaceSolver: B=4096 rows, N=8192 per row.
// Thomas algorithm with precomputed LU factors a (N), b (N-1), c (N-1).
//   fwd: y[i] = x[i] - c[i-1]*y[i-1]        (y[0] = x[0])
//   bwd: z[i] = (y[i] - b[i]*z[i+1])/a[i]   (z[N-1] = y[N-1]/a[N-1])
// Contraction ~0.268/step => HALO=8 zero-init warm-up reproduces exact
// state to ~2.7e-5 relative (absmax ~1e-4, threshold 6.6e-2).
//
// R7: R6 passed at 110us/dispatch but: WRITE_SIZE 168MiB vs 131 ideal
// (VGPR squeezed to 64 < ~70 live -> ~10 floats/thread spilled; the
// squeeze targeted 8 waves/SIMD that LDS (4 blocks/CU) could never give),
// occupancy 40%, VALUBusy 11%, HBM 2.45TB/s -> still latency-bound.
// Changes:
//  - ROWS 16->8: block = 128 thr, LDS 17408 B -> 9 blocks/CU = 18 waves
//    (56% cap) and 9 overlapping block phases per CU.
//  - HALO 16->8: halves warm-up compute; ybuf 48->40 floats -> peak live
//    ~56 regs, fits spill-free. Row stride stays 136 f4 (swizzle needs
//    stride % 8 == 0; bank layout identical to the 0-conflict R6 one).
//  - amdgpu_waves_per_eu(2,5): VGPR budget 102 >> need, stops the
//    allocator from squeezing to 64-with-spill again.
// Kept: prep kernel -> zero-padded position-aligned coef arrays in
// __device__ globals (L2-resident, select-free hot loops, exact 1/a);
// coalesced f4 staging w/ XOR-swizzled LDS; z overwrites consumed x tile;
// coalesced 1KB/wave-instr store-out.

#define NN    8192
#define BB    4096
#define ROWS  8                          // rows per block
#define CCOL  16                         // chunks per block
#define CHUNK 32
#define HALO  8
#define TS4   136                        // tile row stride in float4 (padded,
                                         // multiple of 8 for the XOR swizzle;
                                         // used cols: (CCOL*CHUNK+2*HALO)/4=132)
#define WIN   (CHUNK + HALO)             // 40 floats live in VGPRs per thread
#define NTHR  (ROWS*CCOL)                // 128 threads
#define PADN  (NN + 64)                  // padded coef arrays (max idx 8207)

typedef float yvec_t __attribute__((ext_vector_type(WIN)));

// Padded coefficient arrays, indexed by (position + HALO).
__device__ __align__(16) float g_cm[PADN];   // c[p-1], 0 outside [1, NN-1]
__device__ __align__(16) float g_bp[PADN];   // b[p],   0 outside [0, NN-2]
__device__ __align__(16) float g_ra[PADN];   // 1/a[p], 0 outside [0, NN-1]

__global__ void TriDiag_prep_kernel(
    const float* __restrict__ a,
    const float* __restrict__ b,
    const float* __restrict__ c)
{
    const int i = blockIdx.x * 256 + threadIdx.x;
    if (i >= PADN) return;
    const int p = i - HALO;              // position this slot represents
    g_cm[i] = (p >= 1 && p <= NN-1) ? c[p-1]    : 0.0f;
    g_bp[i] = (p >= 0 && p <= NN-2) ? b[p]      : 0.0f;
    g_ra[i] = (p >= 0 && p <= NN-1) ? 1.0f/a[p] : 0.0f;
}

__global__ __attribute__((amdgpu_flat_work_group_size(NTHR, NTHR),
                          amdgpu_waves_per_eu(2, 5)))
void TriDiagonalLaplaceSolver_kernel(
    const float* __restrict__ x,
    float* __restrict__ out)
{
    __shared__ float4 tile[ROWS * TS4];           // 17408 B; x then z (reused)

    const int t  = threadIdx.x;
    const int g  = blockIdx.x;                    // chunk group, 0..15
    const int r0 = blockIdx.y * ROWS;             // first row of tile
    const int S0 = g * (CCOL*CHUNK) - HALO;       // global col of tile col 0
    const int S4 = S0 >> 2;                       // exact: S0 multiple of 4

    // ---- stage x tile: coalesced float4 loads, XOR-swizzled LDS layout ----
    const float4* __restrict__ x4 = (const float4*)x;
    for (int i = t; i < ROWS*TS4; i += NTHR) {    // 8.5 iters
        const int rr = i / TS4;
        const int c4 = i - rr*TS4;
        const int G4 = S4 + c4;
        float4 v = make_float4(0.0f, 0.0f, 0.0f, 0.0f);
        if ((unsigned)G4 < (unsigned)(NN/4))
            v = x4[(size_t)(r0 + rr) * (NN/4) + G4];
        tile[rr*TS4 + (c4 ^ (rr & 7))] = v;       // bijective in 8-f4 groups
    }
    __syncthreads();

    // ---- per-thread Thomas solve on one 32-col chunk of one row ----
    const int row = t & (ROWS-1);                 // 0..7
    const int cc  = t >> 3;                       // chunk column 0..15
    const int sw  = row;                          // row & 7
    const int tb  = row * TS4;
    const int wb4 = cc * (CHUNK/4);               // 8*cc: warm-up start f4 col
    const int cb4 = wb4 + HALO/4;                 // chunk start f4 col
    const int Jf0 = g*(CCOL*CHUNK) + cc*CHUNK;    // padded idx of warm-up start

    // forward: warm-up q<2 (values discarded; zero-padded multipliers make
    // the g==0,cc==0 warm-up an exact no-op), main q>=2 into ybuf.
    float y = 0.0f;
    yvec_t ybuf;
    #pragma unroll
    for (int q = 0; q < (HALO + WIN)/4; ++q) {    // 12 f4
        const float4 xv  = tile[tb + ((wb4 + q) ^ sw)];
        const float4 cmv = *(const float4*)&g_cm[Jf0 + 4*q];
        const float y0 = xv.x - cmv.x * y;
        const float y1 = xv.y - cmv.y * y0;
        const float y2 = xv.z - cmv.z * y1;
        const float y3 = xv.w - cmv.w * y2;
        y = y3;
        if (q >= HALO/4) {                        // compile-time predicate
            const int k = 4*q - HALO;
            ybuf[k] = y0; ybuf[k+1] = y1; ybuf[k+2] = y2; ybuf[k+3] = y3;
        }
    }

    // backward: warm-up k in [32,40) (discarded; zero-padded b/ra make the
    // last-chunk warm-up exact and give z[N-1]=y[N-1]/a[N-1]), main k<32.
    float z = 0.0f;
    #pragma unroll
    for (int q = WIN/4 - 1; q >= 0; --q) {        // 9..0
        const int j = Jf0 + HALO + 4*q;           // padded idx of ybuf[4q]'s pos
        const float4 bv = *(const float4*)&g_bp[j];
        const float4 rv = *(const float4*)&g_ra[j];
        const int k = 4*q;
        const float z3 = (ybuf[k+3] - bv.w * z ) * rv.w;
        const float z2 = (ybuf[k+2] - bv.z * z3) * rv.z;
        const float z1 = (ybuf[k+1] - bv.y * z2) * rv.y;
        const float z0 = (ybuf[k+0] - bv.x * z1) * rv.x;
        z = z0;
        if (q < CHUNK/4) {                        // compile-time predicate
            ybuf[k] = z0; ybuf[k+1] = z1; ybuf[k+2] = z2; ybuf[k+3] = z3;
        }
    }

    __syncthreads();   // all tile x reads done before z overwrites it

    // ---- z back to LDS (swizzled), then coalesced store-out ----
    #pragma unroll
    for (int q = 0; q < CHUNK/4; ++q) {
        float4 zv;
        zv.x = ybuf[4*q];   zv.y = ybuf[4*q+1];
        zv.z = ybuf[4*q+2]; zv.w = ybuf[4*q+3];
        tile[tb + ((cb4 + q) ^ sw)] = zv;
    }
    __syncthreads();

    float4* __restrict__ o4 = (float4*)out;
    #pragma unroll
    for (int it = 0; it < (ROWS*CCOL*CHUNK/4)/NTHR; ++it) {  // 8 iters
        const int i   = it*NTHR + t;
        const int rr  = i >> 7;                   // 128 f4 per out row
        const int c4o = i & 127;
        const float4 v = tile[rr*TS4 + ((c4o + HALO/4) ^ (rr & 7))];
        o4[(size_t)(r0 + rr) * (NN/4) + g*(CCOL*CHUNK/4) + c4o] = v;
    }
}

extern "C" void kernel_launch(void* const* d_in, const int* in_sizes, int n_in,
                              void* d_out, int out_size, void* d_ws, size_t ws_size,
                              hipStream_t stream) {
    const float* x = (const float*)d_in[0];
    const float* a = (const float*)d_in[1];
    const float* b = (const float*)d_in[2];
    const float* c = (const float*)d_in[3];
    float* out = (float*)d_out;

    TriDiag_prep_kernel<<<dim3((PADN + 255)/256), dim3(256), 0, stream>>>(a, b, c);

    dim3 grid(NN / (CCOL*CHUNK), BB / ROWS);   // 16 x 512 = 8192 blocks
    dim3 block(NTHR);                          // 128 threads = 2 waves
    TriDiagonalLaplaceSolver_kernel<<<grid, block, 0, stream>>>(x, out);
}